// Round 1
// baseline (265.830 us; speedup 1.0000x reference)
//
#include <hip/hip_runtime.h>
#include <hip/hip_bf16.h>

#define B_ 2
#define L_ 2048
#define C_ 1024
#define H_ 16
#define DK_ 64
#define M_ (B_*L_)            // 4096 rows
#define MASK_VALF (-32767.0f)

typedef __attribute__((ext_vector_type(8))) short bf16x8;
typedef __attribute__((ext_vector_type(4))) float f32x4;

static __device__ __forceinline__ short f2bf(float f) {
    __hip_bfloat16 h = __float2bfloat16(f);
    return *reinterpret_cast<short*>(&h);
}

// ---------------- LayerNorm (fp32 -> bf16) ----------------
__global__ __launch_bounds__(256) void ln_kernel(
    const float* __restrict__ qx, const float* __restrict__ kx, const float* __restrict__ vx,
    const float* __restrict__ g, const float* __restrict__ bias,
    short* __restrict__ qn, short* __restrict__ kn, short* __restrict__ vn)
{
    const int row = blockIdx.x;
    const int which = blockIdx.y;
    const float* src = (which == 0) ? qx : (which == 1) ? kx : vx;
    short* dst = (which == 0) ? qn : (which == 1) ? kn : vn;
    src += (size_t)row * C_;
    dst += (size_t)row * C_;
    const int t = threadIdx.x;
    float4 xv = reinterpret_cast<const float4*>(src)[t];
    float s  = xv.x + xv.y + xv.z + xv.w;
    float s2 = xv.x*xv.x + xv.y*xv.y + xv.z*xv.z + xv.w*xv.w;
    #pragma unroll
    for (int off = 32; off > 0; off >>= 1) {
        s  += __shfl_down(s, off);
        s2 += __shfl_down(s2, off);
    }
    __shared__ float red[8];
    const int wid = t >> 6, lane = t & 63;
    if (lane == 0) { red[wid] = s; red[4 + wid] = s2; }
    __syncthreads();
    const float ts  = red[0] + red[1] + red[2] + red[3];
    const float ts2 = red[4] + red[5] + red[6] + red[7];
    const float mu  = ts * (1.0f / C_);
    const float var = ts2 * (1.0f / C_) - mu * mu;
    const float rs  = rsqrtf(var + 1e-5f);
    float4 gv = reinterpret_cast<const float4*>(g)[t];
    float4 bv = reinterpret_cast<const float4*>(bias)[t];
    short4 o;
    o.x = f2bf((xv.x - mu) * rs * gv.x + bv.x);
    o.y = f2bf((xv.y - mu) * rs * gv.y + bv.y);
    o.z = f2bf((xv.z - mu) * rs * gv.z + bv.z);
    o.w = f2bf((xv.w - mu) * rs * gv.w + bv.w);
    reinterpret_cast<short4*>(dst)[t] = o;
}

// ---------------- Weight convert + transpose: wt[n][k] = bf16(w[k][n]) ----------------
__global__ void wconv_kernel(
    const float* __restrict__ wq, const float* __restrict__ wk,
    const float* __restrict__ wv, const float* __restrict__ wo,
    short* __restrict__ wqt, short* __restrict__ wkt,
    short* __restrict__ wvt, short* __restrict__ wot)
{
    const int mz = blockIdx.z;
    const float* w = (mz==0)?wq:(mz==1)?wk:(mz==2)?wv:wo;
    short* wt = (mz==0)?wqt:(mz==1)?wkt:(mz==2)?wvt:wot;
    __shared__ float tile[32][33];
    const int tx = threadIdx.x, ty = threadIdx.y;  // 32 x 8
    const int k0 = blockIdx.x * 32, n0 = blockIdx.y * 32;
    #pragma unroll
    for (int r = 0; r < 4; r++) {
        const int k = k0 + ty + r*8;
        tile[ty + r*8][tx] = w[(size_t)k * 1024 + n0 + tx];
    }
    __syncthreads();
    #pragma unroll
    for (int r = 0; r < 4; r++) {
        const int n = n0 + ty + r*8;
        wt[(size_t)n * 1024 + k0 + tx] = f2bf(tile[tx][ty + r*8]);
    }
}

// ---------------- Mask pack: bit k of word = (maskPAD != 0) ----------------
__global__ __launch_bounds__(256) void maskpack_kernel(
    const int* __restrict__ mask, unsigned long long* __restrict__ bits)
{
    const int gw = blockIdx.x * 4 + (threadIdx.x >> 6);   // word index 0..131071
    const int lane = threadIdx.x & 63;
    const int k = (gw & 31) * 64 + lane;
    const int rowq = gw >> 5;                             // b*L + q
    const int v = mask[(size_t)rowq * L_ + k];
    unsigned long long bal = __ballot(v != 0);
    if (lane == 0) bits[gw] = bal;
}

// ---------------- GEMM core: C128x128 = A[M][1024] * Bt[N][1024]^T, BK=32 ----------------
__device__ __forceinline__ void gemm_core_128(
    const short* __restrict__ Abf, const short* __restrict__ Bt,
    int m0, int n0, short* lds, f32x4 (&acc)[4][4])
{
    const int t = threadIdx.x, w = t >> 6, l = t & 63;
    const int wm = w >> 1, wn = w & 1;
    const int l15 = l & 15, l4 = l >> 4;
    const int srow = t >> 2, scol = (t & 3) * 8;
    const short* aS = Abf + (size_t)(m0 + srow) * 1024 + scol;
    const short* bS = Bt  + (size_t)(n0 + srow) * 1024 + scol;
    char* lb = (char*)lds;
    const int wb = w * 1024;

    for (int kt = 0; kt < 32; ++kt) {
        const int ko = kt * 32;
        __builtin_amdgcn_global_load_lds(
            (const __attribute__((address_space(1))) void*)(aS + ko),
            (__attribute__((address_space(3))) void*)(lb + wb), 16, 0, 0);
        __builtin_amdgcn_global_load_lds(
            (const __attribute__((address_space(1))) void*)(aS + 64*1024 + ko),
            (__attribute__((address_space(3))) void*)(lb + wb + 4096), 16, 0, 0);
        __builtin_amdgcn_global_load_lds(
            (const __attribute__((address_space(1))) void*)(bS + ko),
            (__attribute__((address_space(3))) void*)(lb + 8192 + wb), 16, 0, 0);
        __builtin_amdgcn_global_load_lds(
            (const __attribute__((address_space(1))) void*)(bS + 64*1024 + ko),
            (__attribute__((address_space(3))) void*)(lb + 8192 + wb + 4096), 16, 0, 0);
        __syncthreads();

        bf16x8 af[4], bfr[4];
        #pragma unroll
        for (int fm = 0; fm < 4; fm++)
            af[fm] = *reinterpret_cast<const bf16x8*>(&lds[(wm*64 + fm*16 + l15)*32 + l4*8]);
        #pragma unroll
        for (int fn = 0; fn < 4; fn++)
            bfr[fn] = *reinterpret_cast<const bf16x8*>(&lds[4096 + (wn*64 + fn*16 + l15)*32 + l4*8]);
        #pragma unroll
        for (int fm = 0; fm < 4; fm++)
            #pragma unroll
            for (int fn = 0; fn < 4; fn++)
                acc[fm][fn] = __builtin_amdgcn_mfma_f32_16x16x32_bf16(af[fm], bfr[fn], acc[fm][fn], 0, 0, 0);
        __syncthreads();
    }
}

// ---------------- Projections: q/k/v = LN(x) @ W + b, split heads, q pre-scaled 1/8 ----------------
__global__ __launch_bounds__(256) void gemm_proj(
    const short* __restrict__ qn, const short* __restrict__ kn, const short* __restrict__ vn,
    const short* __restrict__ wqt, const short* __restrict__ wkt, const short* __restrict__ wvt,
    const float* __restrict__ bq, const float* __restrict__ bk, const float* __restrict__ bv,
    short* __restrict__ qb, short* __restrict__ kb, short* __restrict__ vb)
{
    const int pi = blockIdx.y;
    const short* Abf = (pi==0)?qn:(pi==1)?kn:vn;
    const short* Bt  = (pi==0)?wqt:(pi==1)?wkt:wvt;
    const float* bias= (pi==0)?bq:(pi==1)?bk:bv;
    short* outp      = (pi==0)?qb:(pi==1)?kb:vb;
    const float scale = (pi==0)?0.125f:1.0f;

    __shared__ short lds[8192];
    const int bx = blockIdx.x;
    const int m0 = (bx >> 3) * 128, n0 = (bx & 7) * 128;
    f32x4 acc[4][4] = {};
    gemm_core_128(Abf, Bt, m0, n0, lds, acc);

    const int t = threadIdx.x, w = t >> 6, l = t & 63;
    const int wm = w >> 1, wn = w & 1, l15 = l & 15, l4 = l >> 4;
    #pragma unroll
    for (int fn = 0; fn < 4; fn++) {
        const int col = n0 + wn*64 + fn*16 + l15;
        const float bsv = bias[col];
        const int h = col >> 6, dk = col & 63;
        #pragma unroll
        for (int fm = 0; fm < 4; fm++) {
            #pragma unroll
            for (int r = 0; r < 4; r++) {
                const int row = m0 + wm*64 + fm*16 + l4*4 + r;
                const int bb = row >> 11, lr = row & (L_ - 1);
                const float vvf = (acc[fm][fn][r] + bsv) * scale;
                outp[(((size_t)bb*H_ + h)*L_ + lr)*DK_ + dk] = f2bf(vvf);
            }
        }
    }
}

// ---------------- Output projection: out = z @ wo + bo (fp32 out) ----------------
__global__ __launch_bounds__(256) void gemm_out_k(
    const short* __restrict__ zb, const short* __restrict__ wot,
    const float* __restrict__ bo, float* __restrict__ out)
{
    __shared__ short lds[8192];
    const int bx = blockIdx.x;
    const int m0 = (bx >> 3) * 128, n0 = (bx & 7) * 128;
    f32x4 acc[4][4] = {};
    gemm_core_128(zb, wot, m0, n0, lds, acc);

    const int t = threadIdx.x, w = t >> 6, l = t & 63;
    const int wm = w >> 1, wn = w & 1, l15 = l & 15, l4 = l >> 4;
    #pragma unroll
    for (int fn = 0; fn < 4; fn++) {
        const int col = n0 + wn*64 + fn*16 + l15;
        const float bsv = bo[col];
        #pragma unroll
        for (int fm = 0; fm < 4; fm++) {
            #pragma unroll
            for (int r = 0; r < 4; r++) {
                const int row = m0 + wm*64 + fm*16 + l4*4 + r;
                out[(size_t)row * C_ + col] = acc[fm][fn][r] + bsv;
            }
        }
    }
}

// ---------------- Flash attention: per block 64 q-rows of one (b,h) ----------------
__global__ __launch_bounds__(256) void attn_kernel(
    const short* __restrict__ qbuf, const short* __restrict__ kbuf, const short* __restrict__ vbuf,
    const unsigned long long* __restrict__ mbits, short* __restrict__ zb)
{
    __shared__ short Ks[64*72];
    __shared__ short Vt[64*72];
    __shared__ short Ps[4][16*72];
    const int t = threadIdx.x, w = t >> 6, l = t & 63;
    const int l15 = l & 15, l4 = l >> 4;
    const int qt0 = blockIdx.x * 64;
    const int bh = blockIdx.y;
    const int b = bh >> 4, h = bh & 15;
    const size_t base = (size_t)bh * L_ * DK_;

    // Q fragments (A layout), q already scaled by 1/8
    bf16x8 qf[2];
    const int qr = qt0 + w*16 + l15;
    #pragma unroll
    for (int kk = 0; kk < 2; kk++)
        qf[kk] = *reinterpret_cast<const bf16x8*>(&qbuf[base + (size_t)qr*DK_ + kk*32 + l4*8]);

    f32x4 oacc[4];
    #pragma unroll
    for (int nt = 0; nt < 4; nt++) oacc[nt] = (f32x4){0.f, 0.f, 0.f, 0.f};
    float mrow[4], lrow[4];
    #pragma unroll
    for (int r = 0; r < 4; r++) { mrow[r] = -1e30f; lrow[r] = 0.f; }

    const unsigned long long* mb = mbits + ((size_t)b*L_ + qt0 + w*16 + l4*4) * (L_/64);

    for (int kt = 0; kt < L_/64; ++kt) {
        const int k0 = kt * 64;
        // stage K tile (row-major, stride 72) and V tile transposed (stride 72)
        #pragma unroll
        for (int p = 0; p < 2; p++) {
            const int c = t + p*256;
            const int row = c >> 3, c8 = (c & 7) * 8;
            bf16x8 kv = *reinterpret_cast<const bf16x8*>(&kbuf[base + (size_t)(k0+row)*DK_ + c8]);
            *reinterpret_cast<bf16x8*>(&Ks[row*72 + c8]) = kv;
            bf16x8 vv = *reinterpret_cast<const bf16x8*>(&vbuf[base + (size_t)(k0+row)*DK_ + c8]);
            #pragma unroll
            for (int i = 0; i < 8; i++) Vt[(c8+i)*72 + row] = vv[i];
        }
        __syncthreads();

        // S = Q K^T  (16 q-rows per wave x 64 kv-cols)
        f32x4 sfr[4];
        #pragma unroll
        for (int ct = 0; ct < 4; ct++) {
            f32x4 a = (f32x4){0.f, 0.f, 0.f, 0.f};
            #pragma unroll
            for (int kk = 0; kk < 2; kk++) {
                bf16x8 kf = *reinterpret_cast<const bf16x8*>(&Ks[(ct*16 + l15)*72 + kk*32 + l4*8]);
                a = __builtin_amdgcn_mfma_f32_16x16x32_bf16(qf[kk], kf, a, 0, 0, 0);
            }
            sfr[ct] = a;
        }

        unsigned long long mw[4];
        #pragma unroll
        for (int r = 0; r < 4; r++) mw[r] = mb[(size_t)r * (L_/64) + kt];

        float scl[4];
        #pragma unroll
        for (int r = 0; r < 4; r++) {
            float sv[4];
            #pragma unroll
            for (int ct = 0; ct < 4; ct++) {
                const float x = sfr[ct][r];
                sv[ct] = ((mw[r] >> (ct*16 + l15)) & 1ULL) ? x : MASK_VALF;
            }
            float mx = fmaxf(fmaxf(sv[0], sv[1]), fmaxf(sv[2], sv[3]));
            #pragma unroll
            for (int off = 1; off < 16; off <<= 1) mx = fmaxf(mx, __shfl_xor(mx, off));
            const float mnew = fmaxf(mrow[r], mx);
            const float sc = __expf(mrow[r] - mnew);
            float ps = 0.f;
            #pragma unroll
            for (int ct = 0; ct < 4; ct++) {
                const float p = __expf(sv[ct] - mnew);
                ps += p;
                Ps[w][(l4*4 + r)*72 + ct*16 + l15] = f2bf(p);
            }
            #pragma unroll
            for (int off = 1; off < 16; off <<= 1) ps += __shfl_xor(ps, off);
            lrow[r] = lrow[r]*sc + ps;
            mrow[r] = mnew;
            scl[r] = sc;
        }
        #pragma unroll
        for (int nt = 0; nt < 4; nt++)
            #pragma unroll
            for (int r = 0; r < 4; r++) oacc[nt][r] *= scl[r];

        // O += P V   (A = P from LDS, B = V^T rows)
        #pragma unroll
        for (int nt = 0; nt < 4; nt++) {
            #pragma unroll
            for (int kk = 0; kk < 2; kk++) {
                bf16x8 af = *reinterpret_cast<const bf16x8*>(&Ps[w][l15*72 + kk*32 + l4*8]);
                bf16x8 vf = *reinterpret_cast<const bf16x8*>(&Vt[(nt*16 + l15)*72 + kk*32 + l4*8]);
                oacc[nt] = __builtin_amdgcn_mfma_f32_16x16x32_bf16(af, vf, oacc[nt], 0, 0, 0);
            }
        }
        __syncthreads();
    }

    // epilogue: divide by l, write z[b][l][h*64+d] bf16
    #pragma unroll
    for (int nt = 0; nt < 4; nt++) {
        #pragma unroll
        for (int r = 0; r < 4; r++) {
            const int qg = qt0 + w*16 + l4*4 + r;
            const float ov = oacc[nt][r] / lrow[r];
            zb[((size_t)b*L_ + qg)*C_ + h*DK_ + nt*16 + l15] = f2bf(ov);
        }
    }
}

extern "C" void kernel_launch(void* const* d_in, const int* in_sizes, int n_in,
                              void* d_out, int out_size, void* d_ws, size_t ws_size,
                              hipStream_t stream)
{
    (void)in_sizes; (void)n_in; (void)out_size; (void)ws_size;
    const float* qx = (const float*)d_in[0];
    const float* kx = (const float*)d_in[1];
    const float* vx = (const float*)d_in[2];
    const int*   mp = (const int*)d_in[3];
    const float* lg = (const float*)d_in[4];
    const float* lbt= (const float*)d_in[5];
    const float* wq = (const float*)d_in[6];
    const float* bq = (const float*)d_in[7];
    const float* wk = (const float*)d_in[8];
    const float* bk = (const float*)d_in[9];
    const float* wv = (const float*)d_in[10];
    const float* bv = (const float*)d_in[11];
    const float* wo = (const float*)d_in[12];
    const float* bo = (const float*)d_in[13];
    float* out = (float*)d_out;

    short* ws0 = (short*)d_ws;
    short* qn  = ws0;
    short* kn  = qn + (size_t)M_*C_;
    short* vn  = kn + (size_t)M_*C_;
    short* wqt = vn + (size_t)M_*C_;
    short* wkt = wqt + 1024*1024;
    short* wvt = wkt + 1024*1024;
    short* wot = wvt + 1024*1024;
    short* qbuf = wot + 1024*1024;
    short* kbuf = qbuf + (size_t)M_*C_;
    short* vbuf = kbuf + (size_t)M_*C_;
    short* zbuf = vbuf + (size_t)M_*C_;
    unsigned long long* mbits = (unsigned long long*)(zbuf + (size_t)M_*C_);

    hipLaunchKernelGGL(ln_kernel, dim3(M_, 3), dim3(256), 0, stream,
                       qx, kx, vx, lg, lbt, qn, kn, vn);
    hipLaunchKernelGGL(wconv_kernel, dim3(32, 32, 4), dim3(32, 8), 0, stream,
                       wq, wk, wv, wo, wqt, wkt, wvt, wot);
    hipLaunchKernelGGL(maskpack_kernel, dim3((B_*L_*L_/64)/4), dim3(256), 0, stream,
                       mp, mbits);
    hipLaunchKernelGGL(gemm_proj, dim3(256, 3), dim3(256), 0, stream,
                       qn, kn, vn, wqt, wkt, wvt, bq, bk, bv, qbuf, kbuf, vbuf);
    hipLaunchKernelGGL(attn_kernel, dim3(L_/64, B_*H_), dim3(256), 0, stream,
                       qbuf, kbuf, vbuf, mbits, zbuf);
    hipLaunchKernelGGL(gemm_out_k, dim3(256), dim3(256), 0, stream,
                       zbuf, wot, bo, out);
}